// Round 8
// baseline (179.918 us; speedup 1.0000x reference)
//
#include <hip/hip_runtime.h>

#define T_SEQ 1024
#define D_MODEL 1024
#define NH 16
#define DH 64
#define R_SPAN 256.0f

typedef unsigned short ushort_t;
typedef __attribute__((ext_vector_type(8))) short bf16x8;
typedef __attribute__((ext_vector_type(4))) float f32x4;

// RNE conversion (input conversion — feeds all GEMMs)
__device__ __forceinline__ ushort_t f2bf(float f){
  union { float f; unsigned u; } v; v.f = f;
  unsigned r = v.u + 0x7fffu + ((v.u >> 16) & 1u);
  return (ushort_t)(r >> 16);
}

// round-half-up: 2 VALU ops, same 2^-9 rel-err bound (ties only differ)
__device__ __forceinline__ ushort_t f2bf_fast(float f){
  union { float f; unsigned u; } v; v.f = f;
  return (ushort_t)((v.u + 0x8000u) >> 16);
}

__device__ __forceinline__ float fast_exp2(float x){
#if __has_builtin(__builtin_amdgcn_exp2f)
  return __builtin_amdgcn_exp2f(x);
#else
  return __expf(x * 0.69314718056f);
#endif
}

// barrier that drains LDS (lgkmcnt=0) but leaves global loads in flight
__device__ __forceinline__ void barrier_lds_only(){
  __builtin_amdgcn_s_waitcnt(0xC07F);
  __builtin_amdgcn_s_barrier();
}

typedef __attribute__((address_space(1))) void GV;
typedef __attribute__((address_space(3))) void LV;
__device__ __forceinline__ void gld16(const void* g, void* l){
  __builtin_amdgcn_global_load_lds((GV*)g, (LV*)l, 16, 0, 0);
}

// ---------------- fused prep: weight conversion + x conversion + t-partial mean ----
// grid (4, 4, 32), 256 threads.
//   z in [16,32): weight chunks — 256 blocks cover 4x 1024x1024 f32 -> bf16.
//   z in [0,16):  x-part — (dc=bx, b=by, tc=z): convert x to bf16 and produce
//                 16 t-partial means pt[tc][b][d] (final fold in attn prologue).
__global__ void prep_kernel(const float* __restrict__ x,
                            const float* s1, const float* s2, const float* s3, const float* s4,
                            ushort_t* __restrict__ x_bf, ushort_t* __restrict__ w_bf,
                            float* __restrict__ pt){
  const int z = blockIdx.z;
  const int tid = threadIdx.x;

  if (z >= 16){
    const int wz = z - 16;
    const int chunk = wz >> 2;                                      // 0..3
    const int sub = ((wz & 3) << 4) | (blockIdx.y << 2) | blockIdx.x; // 0..63
    const float* ws_[4] = {s1, s2, s3, s4};
    const float* src = ws_[chunk] + (size_t)sub * 16384;            // 16384 floats/sub
    ushort_t* dst = w_bf + ((size_t)chunk << 20) + (size_t)sub * 16384;
#pragma unroll
    for (int i = 0; i < 16; ++i){
      const int o = (i * 256 + tid) * 4;
      float4 v = *(const float4*)(src + o);
      ushort4 u; u.x = f2bf(v.x); u.y = f2bf(v.y); u.z = f2bf(v.z); u.w = f2bf(v.w);
      *(ushort4*)(dst + o) = u;
    }
    return;
  }

  // ---- x part ----
  const int dc = blockIdx.x;   // 0..3 : 256 d each
  const int b  = blockIdx.y;   // 0..3
  const int tc = z;            // 0..15 : 64 t each
  const int dl = tid & 63, tg = tid >> 6;
  const int d = dc * 256 + dl * 4;
  const size_t rowbase = ((size_t)b * T_SEQ + tc * 64 + tg * 16) * D_MODEL + d;
  const float* px = x + rowbase;
  ushort_t* pb = x_bf + rowbase;

  float s0 = 0.f, s1v = 0.f, s2v = 0.f, s3v = 0.f;
#pragma unroll
  for (int tt = 0; tt < 16; ++tt){
    float4 v = *(const float4*)(px + (size_t)tt * D_MODEL);
    ushort4 o; o.x = f2bf(v.x); o.y = f2bf(v.y); o.z = f2bf(v.z); o.w = f2bf(v.w);
    *(ushort4*)(pb + (size_t)tt * D_MODEL) = o;
    s0 += v.x; s1v += v.y; s2v += v.z; s3v += v.w;
  }

  __shared__ float red[4][256];
  *(float4*)&red[tg][dl * 4] = make_float4(s0, s1v, s2v, s3v);
  __syncthreads();
  if (tg == 0){
    float4 a = *(float4*)&red[0][dl * 4];
    float4 c = *(float4*)&red[1][dl * 4];
    float4 e = *(float4*)&red[2][dl * 4];
    float4 g = *(float4*)&red[3][dl * 4];
    float4 t;
    t.x = a.x + c.x + e.x + g.x;
    t.y = a.y + c.y + e.y + g.y;
    t.z = a.z + c.z + e.z + g.z;
    t.w = a.w + c.w + e.w + g.w;
    *(float4*)&pt[((size_t)(tc * 4 + b) << 10) + d] = t;
  }
}

// ---------------- unified GEMM: C = A * B^T, 64x128 tile, 4 waves (256 thr) ----
// R5 gemm_out shape applied to ALL GEMMs. Per-wave 64x32 (acc[4][2], 8 MFMA :
// 6 ds_read) — the R2-proven wave shape — but half-size blocks: QKV grid
// (8,64,3) = 1536 blocks (~3 blocks/CU, tiny tail) vs the old (8,32,3) = 768
// 512-thr blocks (2/CU + a half-occupancy 256-block tail). Independent
// co-resident blocks issue through each other's vmcnt(0)+barrier drains.
// OUT: 0 = bf16 row-major (Q,K) / z==2 V-transposed; 1 = fp32 + bias.
template<int OUT>
__global__ __launch_bounds__(256) void gemm64(
    const ushort_t* __restrict__ A,
    const ushort_t* __restrict__ B,
    void* __restrict__ C,
    const float* __restrict__ bias,
    const int M, const int N, const int K)
{
  __shared__ ushort_t At[2][64 * 32];
  __shared__ ushort_t Bt[2][128 * 32];

  const int z = blockIdx.z;
  const ushort_t* Bz = B + (size_t)z * N * K;

  const int tid = threadIdx.x;
  const int w = tid >> 6, lane = tid & 63;
  const int q = lane >> 4, c = lane & 15;
  const int m0 = blockIdx.y * 64, n0 = blockIdx.x * 128;
  const int wn = w * 32;  // wm = 0 (all waves share the 64-row A strip)

  const int lr = lane >> 2;
  const int lc = (lane & 3) * 8;

  f32x4 acc[4][2] = {};

  // wave w stages A rows [w*16, w*16+16) and B rows [w*32, w*32+32)
  const ushort_t* ga0 = A  + (size_t)(m0 + w * 16 + lr) * K + lc;
  const ushort_t* gb0 = Bz + (size_t)(n0 + w * 32 + lr) * K + lc;

  const int S = K >> 5;
  gld16(ga0,          &At[0][(w * 16) * 32]);
  gld16(gb0,          &Bt[0][(w * 32) * 32]);
  gld16(gb0 + 16 * K, &Bt[0][(w * 32 + 16) * 32]);

  for (int s = 0; s < S; ++s){
    __syncthreads();
    if (s + 1 < S){
      const int k0 = (s + 1) << 5;
      const int nb = (s + 1) & 1;
      gld16(ga0 + k0,          &At[nb][(w * 16) * 32]);
      gld16(gb0 + k0,          &Bt[nb][(w * 32) * 32]);
      gld16(gb0 + 16 * K + k0, &Bt[nb][(w * 32 + 16) * 32]);
    }
    const ushort_t* at = At[s & 1];
    const ushort_t* bt = Bt[s & 1];

    bf16x8 af[4], bfv[2];
#pragma unroll
    for (int i = 0; i < 4; ++i) af[i]  = *(const bf16x8*)&at[(i * 16 + c) * 32 + q * 8];
#pragma unroll
    for (int j = 0; j < 2; ++j) bfv[j] = *(const bf16x8*)&bt[(wn + j * 16 + c) * 32 + q * 8];
#pragma unroll
    for (int i = 0; i < 4; ++i)
#pragma unroll
      for (int j = 0; j < 2; ++j)
        acc[i][j] = __builtin_amdgcn_mfma_f32_16x16x32_bf16(af[i], bfv[j], acc[i][j], 0, 0, 0);
  }

  if (OUT){
#pragma unroll
    for (int i = 0; i < 4; ++i){
#pragma unroll
      for (int j = 0; j < 2; ++j){
        const int row = m0 + i * 16 + q * 4;
        const int col = n0 + wn + j * 16 + c;
#pragma unroll
        for (int r = 0; r < 4; ++r)
          ((float*)C)[(size_t)(row + r) * N + col] = acc[i][j][r] + bias[col];
      }
    }
  } else if (z == 2){
    // V: write transposed vt[b][n][t] so attn can stage V^T directly
    // (64-row tiles never straddle a b-boundary: 1024 % 64 == 0)
    ushort_t* Cv = (ushort_t*)C + (size_t)2 * M * N;
    const int bb = m0 >> 10;
#pragma unroll
    for (int i = 0; i < 4; ++i){
#pragma unroll
      for (int j = 0; j < 2; ++j){
        const int col = n0 + wn + j * 16 + c;
        const int t0 = (m0 & 1023) + i * 16 + q * 4;
        ushort4 pk;
        pk.x = f2bf_fast(acc[i][j][0]); pk.y = f2bf_fast(acc[i][j][1]);
        pk.z = f2bf_fast(acc[i][j][2]); pk.w = f2bf_fast(acc[i][j][3]);
        *(ushort4*)&Cv[((size_t)bb << 20) + (size_t)col * 1024 + t0] = pk;
      }
    }
  } else {
#pragma unroll
    for (int i = 0; i < 4; ++i){
#pragma unroll
      for (int j = 0; j < 2; ++j){
        const int row = m0 + i * 16 + q * 4;
        const int col = n0 + wn + j * 16 + c;
#pragma unroll
        for (int r = 0; r < 4; ++r)
          ((ushort_t*)C + (size_t)z * M * N)[(size_t)(row + r) * N + col] = f2bf_fast(acc[i][j][r]);
      }
    }
  }
}

// ---------------- flash attention with adaptive span (v12) ----------------
// v11 + in-block span: each block computes its (b,h) span logit from the pt
// t-partials (32 L2 loads/thread + dot + wave/LDS reduce), overlapping the
// Q-tile staging + first K/V prefetch latency; the existing __syncthreads
// doubles as the reduction barrier. Removes the span_kernel launch + gap.
// Reduction order identical in every block -> deterministic, consistent zz.
#define LP 72
__global__ __launch_bounds__(512) void attn_kernel(
    const ushort_t* __restrict__ Qg,
    const ushort_t* __restrict__ Kg,
    const ushort_t* __restrict__ Vtg,
    const float* __restrict__ pt,
    const float* __restrict__ Wspan,
    const float* __restrict__ bspan,
    ushort_t* __restrict__ Og)
{
  __shared__ ushort_t Qs[128 * LP];
  __shared__ ushort_t Ks[2][64 * LP];
  __shared__ ushort_t Vt[2][64 * LP];  // [d][j]
  __shared__ ushort_t Ps[8][16 * LP];  // per-wave P band
  __shared__ float spred[8];

  // id = (g/8)*64 + qt*8 + (g%8), g = b*16+h  ->  id%8 == g%8 (XCD locality)
  const int id = blockIdx.x;
  int qt = (id >> 3) & 7;
  if (id >= 256) qt = 7 - qt;  // heavy+light pairing on the shared CU slot
  const int g  = ((id >> 6) << 3) | (id & 7);
  const int b = g >> 4, h = g & 15;
  const int q0 = qt * 128;
  const int tid = threadIdx.x, w = tid >> 6, lane = tid & 63;
  const int q = lane >> 4, c = lane & 15;

  const size_t base = ((size_t)b * T_SEQ) * D_MODEL + (size_t)h * DH;
  const ushort_t* vtb = Vtg + ((size_t)b << 20) + ((size_t)h << 16);

  // load Q tile (128x64): 512 threads x 32 B
  {
    const int row = tid >> 2, seg = tid & 3;
    const uint4* gq = (const uint4*)(Qg + base + (size_t)(q0 + row) * D_MODEL);
    uint4* qs = (uint4*)&Qs[row * LP];
    qs[seg * 2]     = gq[seg * 2];
    qs[seg * 2 + 1] = gq[seg * 2 + 1];
  }

  // staging coords: 64 rows x 8 segs of 8 elements
  const int srow = tid >> 3, sseg = tid & 7;
  const ushort_t* kg = Kg + base + sseg * 8;
  const ushort_t* vg = vtb + (size_t)srow * 1024 + sseg * 8;

  // prefetch first K/V tile (independent of zz)
  uint4 kreg = *(const uint4*)(kg + (size_t)(q0 + srow) * D_MODEL);
  uint4 vreg = *(const uint4*)(vg + q0);

  // in-block span logit: fold 16 t-partials for 2 d's, dot with Wspan row
  {
    const float* wv = Wspan + h * D_MODEL;
    const int i0 = tid * 2;
    float xm0 = 0.f, xm1 = 0.f;
#pragma unroll
    for (int tc = 0; tc < 16; ++tc){
      const float* p = pt + ((size_t)(tc * 4 + b) << 10);
      xm0 += p[i0];
      xm1 += p[i0 + 1];
    }
    float sp = xm0 * wv[i0] + xm1 * wv[i0 + 1];
    for (int off = 32; off; off >>= 1) sp += __shfl_down(sp, off, 64);
    if (lane == 0) spred[w] = sp;
  }

  // Qs + spred visible to all waves
  __syncthreads();

  const float logit = (spred[0] + spred[1] + spred[2] + spred[3] +
                       spred[4] + spred[5] + spred[6] + spred[7]) * (1.0f / T_SEQ)
                      + bspan[h];
  const float zz = (float)T_SEQ / (1.0f + __expf(-logit));
  const int jend = min(T_SEQ, (int)(q0 + 127 + R_SPAN + zz) + 1);

  f32x4 acc_d = {};  // denominator row-sums via MFMA (P x ones)
  f32x4 o[4] = {};

  // all-ones bf16 B-fragment (1.0 = 0x3F80)
  bf16x8 ones8;
#pragma unroll
  for (int i = 0; i < 8; ++i) ones8[i] = (short)0x3F80;

  const int wi0 = q0 + w * 16, wi1 = wi0 + 15;
  int i_row[4];
  float ar4[4];
#pragma unroll
  for (int r = 0; r < 4; ++r){
    i_row[r] = wi0 + q * 4 + r;
    ar4[r] = (R_SPAN + zz + (float)i_row[r]) * (1.0f / R_SPAN);
  }
  // chi lane-constant: (jf*16 + c)/R, hoisted out of the j-loop
  float cjR[4];
#pragma unroll
  for (int jf = 0; jf < 4; ++jf) cjR[jf] = (float)(jf * 16 + c) * (1.0f / R_SPAN);
  const float kexp = 0.125f * 1.44269504f;

  // hoist Q A-fragments (constant over j-loop)
  const bf16x8 aq0 = *(const bf16x8*)&Qs[(w * 16 + c) * LP + q * 8];
  const bf16x8 aq1 = *(const bf16x8*)&Qs[(w * 16 + c) * LP + 32 + q * 8];

  int it = 0;
  for (int j0 = q0; j0 < jend; j0 += 64, ++it){
    const int buf = it & 1;
    // write tile j0 (regs were loaded >=1 compute-phase ago)
    *(uint4*)&Ks[buf][srow * LP + sseg * 8] = kreg;
    *(uint4*)&Vt[buf][srow * LP + sseg * 8] = vreg;
    if (j0 + 64 < jend){
      kreg = *(const uint4*)(kg + (size_t)(j0 + 64 + srow) * D_MODEL);
      vreg = *(const uint4*)(vg + j0 + 64);
    }
    barrier_lds_only();  // LDS writes visible; prefetch stays in flight

    // per-wave skip: fully causal-masked or fully outside span
    if (j0 + 63 < wi0) continue;
    if ((float)(j0 - wi1) > R_SPAN + zz) continue;

    // S = Q K^T  (16x64 band per wave)
    f32x4 s[4] = {};
    __builtin_amdgcn_s_setprio(1);
#pragma unroll
    for (int jf = 0; jf < 4; ++jf){
      bf16x8 bk0 = *(const bf16x8*)&Ks[buf][(jf * 16 + c) * LP + q * 8];
      s[jf] = __builtin_amdgcn_mfma_f32_16x16x32_bf16(aq0, bk0, s[jf], 0, 0, 0);
      bf16x8 bk1 = *(const bf16x8*)&Ks[buf][(jf * 16 + c) * LP + 32 + q * 8];
      s[jf] = __builtin_amdgcn_mfma_f32_16x16x32_bf16(aq1, bk1, s[jf], 0, 0, 0);
    }
    __builtin_amdgcn_s_setprio(0);

    const bool need_mask = (j0 <= wi1);
    const bool full = ((float)(j0 + 63 - wi0) <= zz);

    if (full){
      if (need_mask){
#pragma unroll
        for (int jf = 0; jf < 4; ++jf){
          const int j = j0 + jf * 16 + c;
#pragma unroll
          for (int r = 0; r < 4; ++r){
            float p = fast_exp2(s[jf][r] * kexp);
            p = (j >= i_row[r]) ? p : 0.f;
            Ps[w][(q * 4 + r) * LP + jf * 16 + c] = f2bf_fast(p);
          }
        }
      } else {
#pragma unroll
        for (int jf = 0; jf < 4; ++jf){
#pragma unroll
          for (int r = 0; r < 4; ++r){
            float p = fast_exp2(s[jf][r] * kexp);
            Ps[w][(q * 4 + r) * LP + jf * 16 + c] = f2bf_fast(p);
          }
        }
      }
    } else {
      // ramp: chi = clamp((ar4[r] - j0/R) - cjR[jf], 0, 1)
      const float arj = (float)j0 * (1.0f / R_SPAN);
      if (need_mask){
#pragma unroll
        for (int jf = 0; jf < 4; ++jf){
          const int j = j0 + jf * 16 + c;
#pragma unroll
          for (int r = 0; r < 4; ++r){
            float p = fast_exp2(s[jf][r] * kexp);
            p = (j >= i_row[r]) ? p : 0.f;
            float chi = fminf(fmaxf((ar4[r] - arj) - cjR[jf], 0.f), 1.f);
            Ps[w][(q * 4 + r) * LP + jf * 16 + c] = f2bf_fast(p * chi);
          }
        }
      } else {
#pragma unroll
        for (int jf = 0; jf < 4; ++jf){
#pragma unroll
          for (int r = 0; r < 4; ++r){
            float p = fast_exp2(s[jf][r] * kexp);
            float chi = fminf(fmaxf((ar4[r] - arj) - cjR[jf], 0.f), 1.f);
            Ps[w][(q * 4 + r) * LP + jf * 16 + c] = f2bf_fast(p * chi);
          }
        }
      }
    }

    // O += P V ; acc_d += P x ones (reuses pa fragments; rowsum in all lanes)
    {
      bf16x8 pa0 = *(const bf16x8*)&Ps[w][c * LP + q * 8];
      bf16x8 pa1 = *(const bf16x8*)&Ps[w][c * LP + 32 + q * 8];
      __builtin_amdgcn_s_setprio(1);
      acc_d = __builtin_amdgcn_mfma_f32_16x16x32_bf16(pa0, ones8, acc_d, 0, 0, 0);
      acc_d = __builtin_amdgcn_mfma_f32_16x16x32_bf16(pa1, ones8, acc_d, 0, 0, 0);
#pragma unroll
      for (int nf = 0; nf < 4; ++nf){
        bf16x8 bv0 = *(const bf16x8*)&Vt[buf][(nf * 16 + c) * LP + q * 8];
        o[nf] = __builtin_amdgcn_mfma_f32_16x16x32_bf16(pa0, bv0, o[nf], 0, 0, 0);
        bf16x8 bv1 = *(const bf16x8*)&Vt[buf][(nf * 16 + c) * LP + 32 + q * 8];
        o[nf] = __builtin_amdgcn_mfma_f32_16x16x32_bf16(pa1, bv1, o[nf], 0, 0, 0);
      }
      __builtin_amdgcn_s_setprio(0);
    }
  }

  // epilogue: acc_d[r] already holds the full row-sum in every c-lane
#pragma unroll
  for (int r = 0; r < 4; ++r){
    const float inv = 1.0f / (acc_d[r] + 1e-20f);
    const size_t rowbase = base + (size_t)i_row[r] * D_MODEL;
#pragma unroll
    for (int nf = 0; nf < 4; ++nf){
      Og[rowbase + nf * 16 + c] = f2bf_fast(o[nf][r] * inv);
    }
  }
}

// ---------------- launcher ----------------
extern "C" void kernel_launch(void* const* d_in, const int* in_sizes, int n_in,
                              void* d_out, int out_size, void* d_ws, size_t ws_size,
                              hipStream_t stream)
{
  const float* x     = (const float*)d_in[0];
  const float* Wq    = (const float*)d_in[1];
  const float* Wk    = (const float*)d_in[2];
  const float* Wv    = (const float*)d_in[3];
  const float* Wo    = (const float*)d_in[4];
  const float* bo    = (const float*)d_in[5];
  const float* Wspan = (const float*)d_in[6];
  const float* bspan = (const float*)d_in[7];

  const size_t MT = (size_t)4 * T_SEQ;  // 4096 rows

  ushort_t* x_bf = (ushort_t*)d_ws;                       // 4096*1024 bf16
  ushort_t* w_bf = x_bf + MT * D_MODEL;                   // 4 * 1024*1024 bf16
  ushort_t* qkv  = w_bf + (size_t)4 * D_MODEL * D_MODEL;  // Q,K row-major; V transposed
  ushort_t* attn = qkv + (size_t)3 * MT * D_MODEL;        // 4096*1024 bf16
  float* pt      = (float*)(attn + MT * D_MODEL);         // 16 t-partials x 4 b x 1024 d

  prep_kernel<<<dim3(4, 4, 32), 256, 0, stream>>>(x, Wq, Wk, Wv, Wo, x_bf, w_bf, pt);

  // fused Q,K,V projections (V written transposed): 64x128 tiles, 1536 blocks
  gemm64<0><<<dim3(8, 64, 3), 256, 0, stream>>>(x_bf, w_bf, qkv, nullptr, 4096, 1024, 1024);

  attn_kernel<<<dim3(512), 512, 0, stream>>>(qkv, qkv + MT * D_MODEL,
                                             qkv + 2 * MT * D_MODEL, pt, Wspan, bspan, attn);

  // output projection + bias, fp32 out (64x128 tiles -> 512 blocks, 2+/CU)
  gemm64<1><<<dim3(8, 64, 1), 256, 0, stream>>>(attn, w_bf + (size_t)3 * D_MODEL * D_MODEL,
                                                d_out, bo, 4096, 1024, 1024);
}

// Round 9
// 165.044 us; speedup vs baseline: 1.0901x; 1.0901x over previous
//
#include <hip/hip_runtime.h>

#define T_SEQ 1024
#define D_MODEL 1024
#define NH 16
#define DH 64
#define R_SPAN 256.0f

typedef unsigned short ushort_t;
typedef __attribute__((ext_vector_type(8))) short bf16x8;
typedef __attribute__((ext_vector_type(4))) float f32x4;

// RNE conversion (input conversion — feeds all GEMMs)
__device__ __forceinline__ ushort_t f2bf(float f){
  union { float f; unsigned u; } v; v.f = f;
  unsigned r = v.u + 0x7fffu + ((v.u >> 16) & 1u);
  return (ushort_t)(r >> 16);
}

// round-half-up: 2 VALU ops, same 2^-9 rel-err bound (ties only differ)
__device__ __forceinline__ ushort_t f2bf_fast(float f){
  union { float f; unsigned u; } v; v.f = f;
  return (ushort_t)((v.u + 0x8000u) >> 16);
}

__device__ __forceinline__ float fast_exp2(float x){
#if __has_builtin(__builtin_amdgcn_exp2f)
  return __builtin_amdgcn_exp2f(x);
#else
  return __expf(x * 0.69314718056f);
#endif
}

// barrier that drains LDS (lgkmcnt=0) but leaves global loads in flight
__device__ __forceinline__ void barrier_lds_only(){
  __builtin_amdgcn_s_waitcnt(0xC07F);
  __builtin_amdgcn_s_barrier();
}

typedef __attribute__((address_space(1))) void GV;
typedef __attribute__((address_space(3))) void LV;
__device__ __forceinline__ void gld16(const void* g, void* l){
  __builtin_amdgcn_global_load_lds((GV*)g, (LV*)l, 16, 0, 0);
}

// ---------------- fused prep: weight conversion + x conversion + t-partial mean ----
// grid (4, 4, 32), 256 threads.
//   z in [16,32): weight chunks — 256 blocks cover 4x 1024x1024 f32 -> bf16.
//   z in [0,16):  x-part — (dc=bx, b=by, tc=z): convert x to bf16 and produce
//                 16 t-partial means pt[tc][b][d] (final fold in attn prologue).
__global__ void prep_kernel(const float* __restrict__ x,
                            const float* s1, const float* s2, const float* s3, const float* s4,
                            ushort_t* __restrict__ x_bf, ushort_t* __restrict__ w_bf,
                            float* __restrict__ pt){
  const int z = blockIdx.z;
  const int tid = threadIdx.x;

  if (z >= 16){
    const int wz = z - 16;
    const int chunk = wz >> 2;                                      // 0..3
    const int sub = ((wz & 3) << 4) | (blockIdx.y << 2) | blockIdx.x; // 0..63
    const float* ws_[4] = {s1, s2, s3, s4};
    const float* src = ws_[chunk] + (size_t)sub * 16384;            // 16384 floats/sub
    ushort_t* dst = w_bf + ((size_t)chunk << 20) + (size_t)sub * 16384;
#pragma unroll
    for (int i = 0; i < 16; ++i){
      const int o = (i * 256 + tid) * 4;
      float4 v = *(const float4*)(src + o);
      ushort4 u; u.x = f2bf(v.x); u.y = f2bf(v.y); u.z = f2bf(v.z); u.w = f2bf(v.w);
      *(ushort4*)(dst + o) = u;
    }
    return;
  }

  // ---- x part ----
  const int dc = blockIdx.x;   // 0..3 : 256 d each
  const int b  = blockIdx.y;   // 0..3
  const int tc = z;            // 0..15 : 64 t each
  const int dl = tid & 63, tg = tid >> 6;
  const int d = dc * 256 + dl * 4;
  const size_t rowbase = ((size_t)b * T_SEQ + tc * 64 + tg * 16) * D_MODEL + d;
  const float* px = x + rowbase;
  ushort_t* pb = x_bf + rowbase;

  float s0 = 0.f, s1v = 0.f, s2v = 0.f, s3v = 0.f;
#pragma unroll
  for (int tt = 0; tt < 16; ++tt){
    float4 v = *(const float4*)(px + (size_t)tt * D_MODEL);
    ushort4 o; o.x = f2bf(v.x); o.y = f2bf(v.y); o.z = f2bf(v.z); o.w = f2bf(v.w);
    *(ushort4*)(pb + (size_t)tt * D_MODEL) = o;
    s0 += v.x; s1v += v.y; s2v += v.z; s3v += v.w;
  }

  __shared__ float red[4][256];
  *(float4*)&red[tg][dl * 4] = make_float4(s0, s1v, s2v, s3v);
  __syncthreads();
  if (tg == 0){
    float4 a = *(float4*)&red[0][dl * 4];
    float4 c = *(float4*)&red[1][dl * 4];
    float4 e = *(float4*)&red[2][dl * 4];
    float4 g = *(float4*)&red[3][dl * 4];
    float4 t;
    t.x = a.x + c.x + e.x + g.x;
    t.y = a.y + c.y + e.y + g.y;
    t.z = a.z + c.z + e.z + g.z;
    t.w = a.w + c.w + e.w + g.w;
    *(float4*)&pt[((size_t)(tc * 4 + b) << 10) + d] = t;
  }
}

// ---------------- GEMM: C = A * B^T, 128x128 tile, 8 waves (512 thr) ----------
// R5/R7-proven config. 2-phase double-buffer, gld16 staging. Measured-final:
// 4-wave 128^2 (+3us), counted-vmcnt 3-buf (+3.6us), 64x128 tiles (+13us,
// FETCH 53MB latency-bound) all regressed vs this shape.
template<int FP32OUT>
__global__ __launch_bounds__(512) void gemm_bt(
    const ushort_t* __restrict__ A,
    const ushort_t* __restrict__ B,
    void* __restrict__ C,
    const float* __restrict__ bias,
    const int M, const int N, const int K)
{
  __shared__ ushort_t At[2][128 * 32];
  __shared__ ushort_t Bt[2][128 * 32];

  const int z = blockIdx.z;
  const ushort_t* Bz = B + (size_t)z * N * K;

  const int tid = threadIdx.x;
  const int w = tid >> 6, lane = tid & 63;
  const int q = lane >> 4, c = lane & 15;
  const int m0 = blockIdx.y * 128, n0 = blockIdx.x * 128;
  const int wm = (w >> 2) * 64, wn = (w & 3) * 32;

  const int lr = lane >> 2;
  const int lc = (lane & 3) * 8;

  f32x4 acc[4][2] = {};

  const ushort_t* ga0 = A  + (size_t)(m0 + w * 16 + lr) * K + lc;
  const ushort_t* gb0 = Bz + (size_t)(n0 + w * 16 + lr) * K + lc;

  const int S = K >> 5;
  gld16(ga0, &At[0][(w * 16) * 32]);
  gld16(gb0, &Bt[0][(w * 16) * 32]);

  for (int s = 0; s < S; ++s){
    __syncthreads();  // drains stage(s) [issued a full compute phase ago]
    if (s + 1 < S){
      const int k0 = (s + 1) << 5;
      const int nb = (s + 1) & 1;
      gld16(ga0 + k0, &At[nb][(w * 16) * 32]);
      gld16(gb0 + k0, &Bt[nb][(w * 16) * 32]);
    }
    const ushort_t* at = At[s & 1];
    const ushort_t* bt = Bt[s & 1];

    bf16x8 af[4], bfv[2];
#pragma unroll
    for (int i = 0; i < 4; ++i) af[i]  = *(const bf16x8*)&at[(wm + i * 16 + c) * 32 + q * 8];
#pragma unroll
    for (int j = 0; j < 2; ++j) bfv[j] = *(const bf16x8*)&bt[(wn + j * 16 + c) * 32 + q * 8];
#pragma unroll
    for (int i = 0; i < 4; ++i)
#pragma unroll
      for (int j = 0; j < 2; ++j)
        acc[i][j] = __builtin_amdgcn_mfma_f32_16x16x32_bf16(af[i], bfv[j], acc[i][j], 0, 0, 0);
  }

  if (FP32OUT){
#pragma unroll
    for (int i = 0; i < 4; ++i){
#pragma unroll
      for (int j = 0; j < 2; ++j){
        const int row = m0 + wm + i * 16 + q * 4;
        const int col = n0 + wn + j * 16 + c;
#pragma unroll
        for (int r = 0; r < 4; ++r)
          ((float*)C)[(size_t)(row + r) * N + col] = acc[i][j][r] + bias[col];
      }
    }
  } else if (z == 2){
    // V: write transposed vt[b][n][t] so attn can stage V^T directly
    ushort_t* Cv = (ushort_t*)C + (size_t)2 * M * N;
    const int bb = m0 >> 10;
#pragma unroll
    for (int i = 0; i < 4; ++i){
#pragma unroll
      for (int j = 0; j < 2; ++j){
        const int col = n0 + wn + j * 16 + c;
        const int t0 = (m0 & 1023) + wm + i * 16 + q * 4;
        ushort4 pk;
        pk.x = f2bf_fast(acc[i][j][0]); pk.y = f2bf_fast(acc[i][j][1]);
        pk.z = f2bf_fast(acc[i][j][2]); pk.w = f2bf_fast(acc[i][j][3]);
        *(ushort4*)&Cv[((size_t)bb << 20) + (size_t)col * 1024 + t0] = pk;
      }
    }
  } else {
#pragma unroll
    for (int i = 0; i < 4; ++i){
#pragma unroll
      for (int j = 0; j < 2; ++j){
        const int row = m0 + wm + i * 16 + q * 4;
        const int col = n0 + wn + j * 16 + c;
#pragma unroll
        for (int r = 0; r < 4; ++r)
          ((ushort_t*)C + (size_t)z * M * N)[(size_t)(row + r) * N + col] = f2bf_fast(acc[i][j][r]);
      }
    }
  }
}

// ---------------- out-proj GEMM: 64x128 tile, 4 waves (256 thr) ----------------
// R5-proven: half-size blocks -> grid (8,64) = 512 blocks -> 2 blocks/CU so
// block B issues through block A's barrier drain. (Works for the single-z
// out-proj whose panels stay L2-resident; does NOT transfer to QKV — R8.)
__global__ __launch_bounds__(256) void gemm_out(
    const ushort_t* __restrict__ A,
    const ushort_t* __restrict__ B,
    float* __restrict__ C,
    const float* __restrict__ bias,
    const int M, const int N, const int K)
{
  __shared__ ushort_t At[2][64 * 32];
  __shared__ ushort_t Bt[2][128 * 32];

  const int tid = threadIdx.x;
  const int w = tid >> 6, lane = tid & 63;
  const int q = lane >> 4, c = lane & 15;
  const int m0 = blockIdx.y * 64, n0 = blockIdx.x * 128;
  const int wn = w * 32;  // wm = 0 (all waves share the 64-row strip)

  const int lr = lane >> 2;
  const int lc = (lane & 3) * 8;

  f32x4 acc[4][2] = {};

  // wave w stages A rows [w*16, w*16+16) and B rows [w*32, w*32+32)
  const ushort_t* ga0 = A + (size_t)(m0 + w * 16 + lr) * K + lc;
  const ushort_t* gb0 = B + (size_t)(n0 + w * 32 + lr) * K + lc;

  const int S = K >> 5;
  gld16(ga0,          &At[0][(w * 16) * 32]);
  gld16(gb0,          &Bt[0][(w * 32) * 32]);
  gld16(gb0 + 16 * K, &Bt[0][(w * 32 + 16) * 32]);

  for (int s = 0; s < S; ++s){
    __syncthreads();
    if (s + 1 < S){
      const int k0 = (s + 1) << 5;
      const int nb = (s + 1) & 1;
      gld16(ga0 + k0,          &At[nb][(w * 16) * 32]);
      gld16(gb0 + k0,          &Bt[nb][(w * 32) * 32]);
      gld16(gb0 + 16 * K + k0, &Bt[nb][(w * 32 + 16) * 32]);
    }
    const ushort_t* at = At[s & 1];
    const ushort_t* bt = Bt[s & 1];

    bf16x8 af[4], bfv[2];
#pragma unroll
    for (int i = 0; i < 4; ++i) af[i]  = *(const bf16x8*)&at[(i * 16 + c) * 32 + q * 8];
#pragma unroll
    for (int j = 0; j < 2; ++j) bfv[j] = *(const bf16x8*)&bt[(wn + j * 16 + c) * 32 + q * 8];
#pragma unroll
    for (int i = 0; i < 4; ++i)
#pragma unroll
      for (int j = 0; j < 2; ++j)
        acc[i][j] = __builtin_amdgcn_mfma_f32_16x16x32_bf16(af[i], bfv[j], acc[i][j], 0, 0, 0);
  }

#pragma unroll
  for (int i = 0; i < 4; ++i){
#pragma unroll
    for (int j = 0; j < 2; ++j){
      const int row = m0 + i * 16 + q * 4;
      const int col = n0 + wn + j * 16 + c;
#pragma unroll
      for (int r = 0; r < 4; ++r)
        C[(size_t)(row + r) * N + col] = acc[i][j][r] + bias[col];
    }
  }
}

// ---------------- flash attention with adaptive span (v12) ----------------
// v11 + in-block span: each block computes its (b,h) span logit from the pt
// t-partials (32 L2 loads/thread + dot + wave/LDS reduce), overlapping the
// Q-tile staging + first K/V prefetch latency; the existing __syncthreads
// doubles as the reduction barrier. Removes the span_kernel launch + gap.
// Reduction order identical in every block -> deterministic, consistent zz.
#define LP 72
__global__ __launch_bounds__(512) void attn_kernel(
    const ushort_t* __restrict__ Qg,
    const ushort_t* __restrict__ Kg,
    const ushort_t* __restrict__ Vtg,
    const float* __restrict__ pt,
    const float* __restrict__ Wspan,
    const float* __restrict__ bspan,
    ushort_t* __restrict__ Og)
{
  __shared__ ushort_t Qs[128 * LP];
  __shared__ ushort_t Ks[2][64 * LP];
  __shared__ ushort_t Vt[2][64 * LP];  // [d][j]
  __shared__ ushort_t Ps[8][16 * LP];  // per-wave P band
  __shared__ float spred[8];

  // id = (g/8)*64 + qt*8 + (g%8), g = b*16+h  ->  id%8 == g%8 (XCD locality)
  const int id = blockIdx.x;
  int qt = (id >> 3) & 7;
  if (id >= 256) qt = 7 - qt;  // heavy+light pairing on the shared CU slot
  const int g  = ((id >> 6) << 3) | (id & 7);
  const int b = g >> 4, h = g & 15;
  const int q0 = qt * 128;
  const int tid = threadIdx.x, w = tid >> 6, lane = tid & 63;
  const int q = lane >> 4, c = lane & 15;

  const size_t base = ((size_t)b * T_SEQ) * D_MODEL + (size_t)h * DH;
  const ushort_t* vtb = Vtg + ((size_t)b << 20) + ((size_t)h << 16);

  // load Q tile (128x64): 512 threads x 32 B
  {
    const int row = tid >> 2, seg = tid & 3;
    const uint4* gq = (const uint4*)(Qg + base + (size_t)(q0 + row) * D_MODEL);
    uint4* qs = (uint4*)&Qs[row * LP];
    qs[seg * 2]     = gq[seg * 2];
    qs[seg * 2 + 1] = gq[seg * 2 + 1];
  }

  // staging coords: 64 rows x 8 segs of 8 elements
  const int srow = tid >> 3, sseg = tid & 7;
  const ushort_t* kg = Kg + base + sseg * 8;
  const ushort_t* vg = vtb + (size_t)srow * 1024 + sseg * 8;

  // prefetch first K/V tile (independent of zz)
  uint4 kreg = *(const uint4*)(kg + (size_t)(q0 + srow) * D_MODEL);
  uint4 vreg = *(const uint4*)(vg + q0);

  // in-block span logit: fold 16 t-partials for 2 d's, dot with Wspan row
  {
    const float* wv = Wspan + h * D_MODEL;
    const int i0 = tid * 2;
    float xm0 = 0.f, xm1 = 0.f;
#pragma unroll
    for (int tc = 0; tc < 16; ++tc){
      const float* p = pt + ((size_t)(tc * 4 + b) << 10);
      xm0 += p[i0];
      xm1 += p[i0 + 1];
    }
    float sp = xm0 * wv[i0] + xm1 * wv[i0 + 1];
    for (int off = 32; off; off >>= 1) sp += __shfl_down(sp, off, 64);
    if (lane == 0) spred[w] = sp;
  }

  // Qs + spred visible to all waves
  __syncthreads();

  const float logit = (spred[0] + spred[1] + spred[2] + spred[3] +
                       spred[4] + spred[5] + spred[6] + spred[7]) * (1.0f / T_SEQ)
                      + bspan[h];
  const float zz = (float)T_SEQ / (1.0f + __expf(-logit));
  const int jend = min(T_SEQ, (int)(q0 + 127 + R_SPAN + zz) + 1);

  f32x4 acc_d = {};  // denominator row-sums via MFMA (P x ones)
  f32x4 o[4] = {};

  // all-ones bf16 B-fragment (1.0 = 0x3F80)
  bf16x8 ones8;
#pragma unroll
  for (int i = 0; i < 8; ++i) ones8[i] = (short)0x3F80;

  const int wi0 = q0 + w * 16, wi1 = wi0 + 15;
  int i_row[4];
  float ar4[4];
#pragma unroll
  for (int r = 0; r < 4; ++r){
    i_row[r] = wi0 + q * 4 + r;
    ar4[r] = (R_SPAN + zz + (float)i_row[r]) * (1.0f / R_SPAN);
  }
  // chi lane-constant: (jf*16 + c)/R, hoisted out of the j-loop
  float cjR[4];
#pragma unroll
  for (int jf = 0; jf < 4; ++jf) cjR[jf] = (float)(jf * 16 + c) * (1.0f / R_SPAN);
  const float kexp = 0.125f * 1.44269504f;

  // hoist Q A-fragments (constant over j-loop)
  const bf16x8 aq0 = *(const bf16x8*)&Qs[(w * 16 + c) * LP + q * 8];
  const bf16x8 aq1 = *(const bf16x8*)&Qs[(w * 16 + c) * LP + 32 + q * 8];

  int it = 0;
  for (int j0 = q0; j0 < jend; j0 += 64, ++it){
    const int buf = it & 1;
    // write tile j0 (regs were loaded >=1 compute-phase ago)
    *(uint4*)&Ks[buf][srow * LP + sseg * 8] = kreg;
    *(uint4*)&Vt[buf][srow * LP + sseg * 8] = vreg;
    if (j0 + 64 < jend){
      kreg = *(const uint4*)(kg + (size_t)(j0 + 64 + srow) * D_MODEL);
      vreg = *(const uint4*)(vg + j0 + 64);
    }
    barrier_lds_only();  // LDS writes visible; prefetch stays in flight

    // per-wave skip: fully causal-masked or fully outside span
    if (j0 + 63 < wi0) continue;
    if ((float)(j0 - wi1) > R_SPAN + zz) continue;

    // S = Q K^T  (16x64 band per wave)
    f32x4 s[4] = {};
    __builtin_amdgcn_s_setprio(1);
#pragma unroll
    for (int jf = 0; jf < 4; ++jf){
      bf16x8 bk0 = *(const bf16x8*)&Ks[buf][(jf * 16 + c) * LP + q * 8];
      s[jf] = __builtin_amdgcn_mfma_f32_16x16x32_bf16(aq0, bk0, s[jf], 0, 0, 0);
      bf16x8 bk1 = *(const bf16x8*)&Ks[buf][(jf * 16 + c) * LP + 32 + q * 8];
      s[jf] = __builtin_amdgcn_mfma_f32_16x16x32_bf16(aq1, bk1, s[jf], 0, 0, 0);
    }
    __builtin_amdgcn_s_setprio(0);

    const bool need_mask = (j0 <= wi1);
    const bool full = ((float)(j0 + 63 - wi0) <= zz);

    if (full){
      if (need_mask){
#pragma unroll
        for (int jf = 0; jf < 4; ++jf){
          const int j = j0 + jf * 16 + c;
#pragma unroll
          for (int r = 0; r < 4; ++r){
            float p = fast_exp2(s[jf][r] * kexp);
            p = (j >= i_row[r]) ? p : 0.f;
            Ps[w][(q * 4 + r) * LP + jf * 16 + c] = f2bf_fast(p);
          }
        }
      } else {
#pragma unroll
        for (int jf = 0; jf < 4; ++jf){
#pragma unroll
          for (int r = 0; r < 4; ++r){
            float p = fast_exp2(s[jf][r] * kexp);
            Ps[w][(q * 4 + r) * LP + jf * 16 + c] = f2bf_fast(p);
          }
        }
      }
    } else {
      // ramp: chi = clamp((ar4[r] - j0/R) - cjR[jf], 0, 1)
      const float arj = (float)j0 * (1.0f / R_SPAN);
      if (need_mask){
#pragma unroll
        for (int jf = 0; jf < 4; ++jf){
          const int j = j0 + jf * 16 + c;
#pragma unroll
          for (int r = 0; r < 4; ++r){
            float p = fast_exp2(s[jf][r] * kexp);
            p = (j >= i_row[r]) ? p : 0.f;
            float chi = fminf(fmaxf((ar4[r] - arj) - cjR[jf], 0.f), 1.f);
            Ps[w][(q * 4 + r) * LP + jf * 16 + c] = f2bf_fast(p * chi);
          }
        }
      } else {
#pragma unroll
        for (int jf = 0; jf < 4; ++jf){
#pragma unroll
          for (int r = 0; r < 4; ++r){
            float p = fast_exp2(s[jf][r] * kexp);
            float chi = fminf(fmaxf((ar4[r] - arj) - cjR[jf], 0.f), 1.f);
            Ps[w][(q * 4 + r) * LP + jf * 16 + c] = f2bf_fast(p * chi);
          }
        }
      }
    }

    // O += P V ; acc_d += P x ones (reuses pa fragments; rowsum in all lanes)
    {
      bf16x8 pa0 = *(const bf16x8*)&Ps[w][c * LP + q * 8];
      bf16x8 pa1 = *(const bf16x8*)&Ps[w][c * LP + 32 + q * 8];
      __builtin_amdgcn_s_setprio(1);
      acc_d = __builtin_amdgcn_mfma_f32_16x16x32_bf16(pa0, ones8, acc_d, 0, 0, 0);
      acc_d = __builtin_amdgcn_mfma_f32_16x16x32_bf16(pa1, ones8, acc_d, 0, 0, 0);
#pragma unroll
      for (int nf = 0; nf < 4; ++nf){
        bf16x8 bv0 = *(const bf16x8*)&Vt[buf][(nf * 16 + c) * LP + q * 8];
        o[nf] = __builtin_amdgcn_mfma_f32_16x16x32_bf16(pa0, bv0, o[nf], 0, 0, 0);
        bf16x8 bv1 = *(const bf16x8*)&Vt[buf][(nf * 16 + c) * LP + 32 + q * 8];
        o[nf] = __builtin_amdgcn_mfma_f32_16x16x32_bf16(pa1, bv1, o[nf], 0, 0, 0);
      }
      __builtin_amdgcn_s_setprio(0);
    }
  }

  // epilogue: acc_d[r] already holds the full row-sum in every c-lane
#pragma unroll
  for (int r = 0; r < 4; ++r){
    const float inv = 1.0f / (acc_d[r] + 1e-20f);
    const size_t rowbase = base + (size_t)i_row[r] * D_MODEL;
#pragma unroll
    for (int nf = 0; nf < 4; ++nf){
      Og[rowbase + nf * 16 + c] = f2bf_fast(o[nf][r] * inv);
    }
  }
}

// ---------------- launcher ----------------
extern "C" void kernel_launch(void* const* d_in, const int* in_sizes, int n_in,
                              void* d_out, int out_size, void* d_ws, size_t ws_size,
                              hipStream_t stream)
{
  const float* x     = (const float*)d_in[0];
  const float* Wq    = (const float*)d_in[1];
  const float* Wk    = (const float*)d_in[2];
  const float* Wv    = (const float*)d_in[3];
  const float* Wo    = (const float*)d_in[4];
  const float* bo    = (const float*)d_in[5];
  const float* Wspan = (const float*)d_in[6];
  const float* bspan = (const float*)d_in[7];

  const size_t MT = (size_t)4 * T_SEQ;  // 4096 rows

  ushort_t* x_bf = (ushort_t*)d_ws;                       // 4096*1024 bf16
  ushort_t* w_bf = x_bf + MT * D_MODEL;                   // 4 * 1024*1024 bf16
  ushort_t* qkv  = w_bf + (size_t)4 * D_MODEL * D_MODEL;  // Q,K row-major; V transposed
  ushort_t* attn = qkv + (size_t)3 * MT * D_MODEL;        // 4096*1024 bf16
  float* pt      = (float*)(attn + MT * D_MODEL);         // 16 t-partials x 4 b x 1024 d

  prep_kernel<<<dim3(4, 4, 32), 256, 0, stream>>>(x, Wq, Wk, Wv, Wo, x_bf, w_bf, pt);

  // fused Q,K,V projections (V written transposed)
  gemm_bt<0><<<dim3(8, 32, 3), 512, 0, stream>>>(x_bf, w_bf, qkv, nullptr, 4096, 1024, 1024);

  attn_kernel<<<dim3(512), 512, 0, stream>>>(qkv, qkv + MT * D_MODEL,
                                             qkv + 2 * MT * D_MODEL, pt, Wspan, bspan, attn);

  // output projection + bias, fp32 out (64x128 tiles -> 512 blocks, 2/CU)
  gemm_out<<<dim3(8, 64), 256, 0, stream>>>(attn, w_bf + (size_t)3 * D_MODEL * D_MODEL,
                                            (float*)d_out, bo, 4096, 1024, 1024);
}